// Round 1
// baseline (6730.701 us; speedup 1.0000x reference)
//
#include <hip/hip_runtime.h>
#include <cstdint>

#define Tt 512
#define Bb 512
#define Ii 128
#define Hh 128
#define G4 512   // 4*H
#define S1 65    // stack slots
#define CH 64    // steps per chunk
#define NSTEP 511

__device__ __forceinline__ float sigm(float x) {
    float e = __builtin_amdgcn_exp2f(x * -1.442695041f);
    return __builtin_amdgcn_rcpf(1.0f + e);
}
__device__ __forceinline__ float tanhx(float x) {
    float e = __builtin_amdgcn_exp2f(x * 2.885390082f);   // exp(2x)
    return 1.0f - 2.0f * __builtin_amdgcn_rcpf(e + 1.0f);
}

// ---------------- Input GEMM: Gx = x @ W_ih^T + (b_ih + b_hh) ----------------
// One block = 64 x-rows; thread r holds W_ih[r][:] in 32 float4 VGPRs.
__global__ __launch_bounds__(512) void gx_gemm(
    const float* __restrict__ x,      // (rows, 128), chunk base
    const float* __restrict__ W_ih,   // (512, 128)
    const float* __restrict__ b_ih,
    const float* __restrict__ b_hh,
    float* __restrict__ gx)           // (rows, 512)
{
    const int r = threadIdx.x;
    float4 w[32];
    const float4* wp = (const float4*)(W_ih + r * Ii);
#pragma unroll
    for (int j = 0; j < 32; ++j) w[j] = wp[j];
    const float bias = b_ih[r] + b_hh[r];

    __shared__ float xs[64 * Ii];     // 32 KB
    const int m0 = blockIdx.x * 64;
    {
        const float4* src = (const float4*)(x + (size_t)m0 * Ii);
        float4* dst = (float4*)xs;
#pragma unroll
        for (int j = 0; j < 4; ++j) dst[threadIdx.x + j * 512] = src[threadIdx.x + j * 512];
    }
    __syncthreads();

#pragma unroll 2
    for (int mi = 0; mi < 64; ++mi) {
        const float4* xr = (const float4*)(xs + mi * Ii);
        float a0 = 0.f, a1 = 0.f, a2 = 0.f, a3 = 0.f;
#pragma unroll
        for (int j = 0; j < 32; j += 4) {
            float4 p = xr[j + 0];
            float4 q = xr[j + 1];
            float4 u = xr[j + 2];
            float4 v = xr[j + 3];
            a0 = fmaf(w[j+0].x, p.x, a0); a0 = fmaf(w[j+0].y, p.y, a0);
            a0 = fmaf(w[j+0].z, p.z, a0); a0 = fmaf(w[j+0].w, p.w, a0);
            a1 = fmaf(w[j+1].x, q.x, a1); a1 = fmaf(w[j+1].y, q.y, a1);
            a1 = fmaf(w[j+1].z, q.z, a1); a1 = fmaf(w[j+1].w, q.w, a1);
            a2 = fmaf(w[j+2].x, u.x, a2); a2 = fmaf(w[j+2].y, u.y, a2);
            a2 = fmaf(w[j+2].z, u.z, a2); a2 = fmaf(w[j+2].w, u.w, a2);
            a3 = fmaf(w[j+3].x, v.x, a3); a3 = fmaf(w[j+3].y, v.y, a3);
            a3 = fmaf(w[j+3].z, v.z, a3); a3 = fmaf(w[j+3].w, v.w, a3);
        }
        gx[(size_t)(m0 + mi) * G4 + r] = ((a0 + a1) + (a2 + a3)) + bias;
    }
}

// ---------------- Recurrence: one block per batch element ----------------
// 1024 threads: thread (r = tid>>1, half = tid&1) holds W_hh[r][half*64 .. +64)
// in 16 float4 VGPRs. Stack state lives in LDS for the whole chunk.
__global__ __launch_bounds__(1024) void rec_step(
    const float* __restrict__ gxc,    // (steps, B, 512) chunk
    const int* __restrict__ ops,      // (T, B)
    const float* __restrict__ W_hh,   // (512, 128)
    const float* __restrict__ init_h,
    const float* __restrict__ init_c,
    float* __restrict__ out,          // (NSTEP, B, H)
    float* __restrict__ h_save,
    float* __restrict__ c_save,
    int* __restrict__ pt_save,
    int t0, int steps, int first, int last)
{
    const int b = blockIdx.x;
    const int tid = threadIdx.x;
    const int r = tid >> 1;
    const int half = tid & 1;

    __shared__ float h_st[S1 * Hh];   // 33.3 KB
    __shared__ float c_st[S1 * Hh];   // 33.3 KB
    __shared__ float gates[G4];       // 2 KB
    __shared__ int opsb[CH + 1];

    float4 w[16];
    const float4* wp = (const float4*)(W_hh + r * Hh + half * 64);
#pragma unroll
    for (int j = 0; j < 16; ++j) w[j] = wp[j];

    if (first) {
        for (int i = tid; i < S1 * Hh; i += 1024) {
            h_st[i] = (i < Hh) ? init_h[i] : 0.f;
            c_st[i] = (i < Hh) ? init_c[i] : 0.f;
        }
    } else {
        const float* hs = h_save + (size_t)b * (S1 * Hh);
        const float* cs = c_save + (size_t)b * (S1 * Hh);
        for (int i = tid; i < S1 * Hh; i += 1024) { h_st[i] = hs[i]; c_st[i] = cs[i]; }
    }
    for (int i = tid; i <= steps; i += 1024) opsb[i] = ops[(size_t)(t0 + i) * Bb + b];
    int pt = first ? 0 : pt_save[b];
    __syncthreads();

    for (int s = 0; s < steps; ++s) {
        pt += opsb[s];                       // pt = pts[t0+s]
        const int opn = opsb[s + 1];         // ops[t0+s+1]
        const float gx = gxc[((size_t)s * Bb + b) * G4 + r];  // prefetch, used post-dot

        const float4* hv4 = (const float4*)(h_st + pt * Hh + half * 64);
        float a0 = 0.f, a1 = 0.f, a2 = 0.f, a3 = 0.f;
#pragma unroll
        for (int j = 0; j < 16; j += 4) {
            float4 p = hv4[j + 0];
            float4 q = hv4[j + 1];
            float4 u = hv4[j + 2];
            float4 v = hv4[j + 3];
            a0 = fmaf(w[j+0].x, p.x, a0); a0 = fmaf(w[j+0].y, p.y, a0);
            a0 = fmaf(w[j+0].z, p.z, a0); a0 = fmaf(w[j+0].w, p.w, a0);
            a1 = fmaf(w[j+1].x, q.x, a1); a1 = fmaf(w[j+1].y, q.y, a1);
            a1 = fmaf(w[j+1].z, q.z, a1); a1 = fmaf(w[j+1].w, q.w, a1);
            a2 = fmaf(w[j+2].x, u.x, a2); a2 = fmaf(w[j+2].y, u.y, a2);
            a2 = fmaf(w[j+2].z, u.z, a2); a2 = fmaf(w[j+2].w, u.w, a2);
            a3 = fmaf(w[j+3].x, v.x, a3); a3 = fmaf(w[j+3].y, v.y, a3);
            a3 = fmaf(w[j+3].z, v.z, a3); a3 = fmaf(w[j+3].w, v.w, a3);
        }
        float acc = (a0 + a1) + (a2 + a3);
        acc += __shfl_xor(acc, 1);           // combine k-halves (lane pairs)
        gates[r] = acc + gx;                 // both halves write same value (benign)
        __syncthreads();

        if (tid < Hh) {
            const int h = tid;
            float gi = gates[h];
            float gf = gates[Hh + h];
            float gg = gates[2 * Hh + h];
            float go = gates[3 * Hh + h];
            float cc = c_st[pt * Hh + h];
            float ch = h_st[pt * Hh + h];
            float ph = h_st[((pt + S1 - 1) % S1) * Hh + h];
            float nc = sigm(gf) * cc + sigm(gi) * tanhx(gg);
            float nh = sigm(go) * tanhx(nc);
            c_st[(pt + 1) * Hh + h] = nc;
            h_st[(pt + 1) * Hh + h] = nh;
            float opf = (float)opn;
            float af = fabsf(opf);
            float ret = (nh * (1.f + opf) + ph * (1.f - opf)) * af + ch * (1.f - af);
            out[((size_t)(t0 + s) * Bb + b) * Hh + h] = ret;
        }
        __syncthreads();
    }

    if (!last) {
        float* hs = h_save + (size_t)b * (S1 * Hh);
        float* cs = c_save + (size_t)b * (S1 * Hh);
        for (int i = tid; i < S1 * Hh; i += 1024) { hs[i] = h_st[i]; cs[i] = c_st[i]; }
        if (tid == 0) pt_save[b] = pt;
    }
}

extern "C" void kernel_launch(void* const* d_in, const int* in_sizes, int n_in,
                              void* d_out, int out_size, void* d_ws, size_t ws_size,
                              hipStream_t stream) {
    const float* inputs = (const float*)d_in[0];
    const int*   ops    = (const int*)d_in[1];
    const float* W_ih   = (const float*)d_in[2];
    const float* W_hh   = (const float*)d_in[3];
    const float* b_ih   = (const float*)d_in[4];
    const float* b_hh   = (const float*)d_in[5];
    const float* init_h = (const float*)d_in[6];
    const float* init_c = (const float*)d_in[7];
    float* out = (float*)d_out;

    // Workspace carve-up (~101 MB total):
    //   gxbuf: CH*B*512 fp32 = 64 MB; h_save/c_save: B*65*128 fp32 = 17 MB each; pt_save: 2 KB
    float* gxbuf  = (float*)d_ws;
    float* h_save = gxbuf + (size_t)CH * Bb * G4;
    float* c_save = h_save + (size_t)Bb * S1 * Hh;
    int*   pt_save = (int*)(c_save + (size_t)Bb * S1 * Hh);

    int t0 = 0;
    while (t0 < NSTEP) {
        const int steps = (NSTEP - t0 < CH) ? (NSTEP - t0) : CH;
        const int rows = steps * Bb;
        gx_gemm<<<rows / 64, 512, 0, stream>>>(
            inputs + (size_t)t0 * Bb * Ii, W_ih, b_ih, b_hh, gxbuf);
        rec_step<<<Bb, 1024, 0, stream>>>(
            gxbuf, ops, W_hh, init_h, init_c, out,
            h_save, c_save, pt_save, t0, steps,
            (t0 == 0) ? 1 : 0, (t0 + steps >= NSTEP) ? 1 : 0);
        t0 += steps;
    }
}

// Round 2
// 2303.706 us; speedup vs baseline: 2.9217x; 2.9217x over previous
//
#include <hip/hip_runtime.h>
#include <cstdint>

#define Tt 512
#define Bb 512
#define Ii 128
#define Hh 128
#define G4 512   // 4*H
#define S1 65    // stack slots
#define CH 64    // steps per chunk
#define NSTEP 511

__device__ __forceinline__ float sigm(float x) {
    float e = __builtin_amdgcn_exp2f(x * -1.442695041f);
    return __builtin_amdgcn_rcpf(1.0f + e);
}
__device__ __forceinline__ float tanhx(float x) {
    float e = __builtin_amdgcn_exp2f(x * 2.885390082f);   // exp(2x)
    return 1.0f - 2.0f * __builtin_amdgcn_rcpf(e + 1.0f);
}
// broadcast lane l of v to all lanes (v_readlane -> SGPR operand of v_fmac)
__device__ __forceinline__ float rl(float v, int l) {
    return __int_as_float(__builtin_amdgcn_readlane(__float_as_int(v), l));
}

// ---------------- Input GEMM: gx = x @ W_ih^T + (b_ih + b_hh) ----------------
// 512 threads = 512 output gates; thread keeps W_ih[r][:] in 32 float4 VGPRs
// (launch_bounds(512,2) -> 256-VGPR cap so they stay resident). Per row the
// wave holds x in 2 VGPRs (x[lane], x[64+lane]) and broadcasts via readlane.
__global__ __launch_bounds__(512, 2) void gx_gemm(
    const float* __restrict__ x,      // (rows, 128), chunk base
    const float* __restrict__ W_ih,   // (512, 128)
    const float* __restrict__ b_ih,
    const float* __restrict__ b_hh,
    float* __restrict__ gx)           // (rows, 512)
{
    const int tid = threadIdx.x;
    const int lane = tid & 63;
    float4 w4[32];
    const float4* wp = (const float4*)(W_ih + tid * Ii);
#pragma unroll
    for (int j = 0; j < 32; ++j) w4[j] = wp[j];
    const float bias = b_ih[tid] + b_hh[tid];

    __shared__ float xs[64 * Ii];     // 32 KB
    const size_t m0 = (size_t)blockIdx.x * 64;
    {
        const float4* src = (const float4*)(x + m0 * Ii);
        float4* dst = (float4*)xs;
#pragma unroll
        for (int j = 0; j < 4; ++j) dst[tid + j * 512] = src[tid + j * 512];
    }
    __syncthreads();

    for (int mi = 0; mi < 64; ++mi) {
        const float hv0 = xs[mi * Ii + lane];
        const float hv1 = xs[mi * Ii + 64 + lane];
        float a0 = 0.f, a1 = 0.f, a2 = 0.f, a3 = 0.f;
#pragma unroll
        for (int j = 0; j < 16; ++j) {
            const float4 W = w4[j];          // k = 4j .. 4j+3  (first half)
            a0 = fmaf(W.x, rl(hv0, 4 * j + 0), a0);
            a1 = fmaf(W.y, rl(hv0, 4 * j + 1), a1);
            a2 = fmaf(W.z, rl(hv0, 4 * j + 2), a2);
            a3 = fmaf(W.w, rl(hv0, 4 * j + 3), a3);
        }
#pragma unroll
        for (int j = 0; j < 16; ++j) {
            const float4 W = w4[16 + j];     // k = 64+4j ..  (second half)
            a0 = fmaf(W.x, rl(hv1, 4 * j + 0), a0);
            a1 = fmaf(W.y, rl(hv1, 4 * j + 1), a1);
            a2 = fmaf(W.z, rl(hv1, 4 * j + 2), a2);
            a3 = fmaf(W.w, rl(hv1, 4 * j + 3), a3);
        }
        gx[(m0 + mi) * G4 + tid] = ((a0 + a1) + (a2 + a3)) + bias;
    }
}

// ---------------- Recurrence: one block (512 threads) per batch element -----
// thread tid: khalf = tid>>8 (k-range half), rr = tid&255 -> gates rr, rr+256.
// Weights for both gates (2x64 floats) resident in VGPRs. Per step the wave
// does ONE ds_read_b32 of h (lane k) and readlane-broadcasts; each broadcast
// feeds 2 FMAs. Partials combined through a small LDS buffer.
__global__ __launch_bounds__(512, 2) void rec_step(
    const float* __restrict__ gxc,    // (steps, B, 512) chunk
    const int* __restrict__ ops,      // (T, B)
    const float* __restrict__ W_hh,   // (512, 128)
    const float* __restrict__ init_h,
    const float* __restrict__ init_c,
    float* __restrict__ out,          // (NSTEP, B, H)
    float* __restrict__ h_save,
    float* __restrict__ c_save,
    int* __restrict__ pt_save,
    int t0, int steps, int first, int last)
{
    const int b = blockIdx.x;
    const int tid = threadIdx.x;
    const int lane = tid & 63;
    const int khalf = tid >> 8;       // wave-uniform (waves 0-3: 0, waves 4-7: 1)
    const int rr = tid & 255;

    __shared__ float h_st[S1 * Hh];   // 33.3 KB
    __shared__ float c_st[S1 * Hh];   // 33.3 KB
    __shared__ float gpart[2 * G4];   // 4 KB partial sums [khalf][gate]
    __shared__ int opsb[CH + 1];

    float4 w0[16], w1[16];
    {
        const float4* p0 = (const float4*)(W_hh + rr * Hh + khalf * 64);
        const float4* p1 = (const float4*)(W_hh + (rr + 256) * Hh + khalf * 64);
#pragma unroll
        for (int j = 0; j < 16; ++j) { w0[j] = p0[j]; w1[j] = p1[j]; }
    }

    if (first) {
        for (int i = tid; i < S1 * Hh; i += 512) {
            h_st[i] = (i < Hh) ? init_h[i] : 0.f;
            c_st[i] = (i < Hh) ? init_c[i] : 0.f;
        }
    } else {
        const float* hs = h_save + (size_t)b * (S1 * Hh);
        const float* cs = c_save + (size_t)b * (S1 * Hh);
        for (int i = tid; i < S1 * Hh; i += 512) { h_st[i] = hs[i]; c_st[i] = cs[i]; }
    }
    for (int i = tid; i <= steps; i += 512) opsb[i] = ops[(size_t)(t0 + i) * Bb + b];
    int pt = first ? 0 : pt_save[b];
    __syncthreads();

    for (int s = 0; s < steps; ++s) {
        pt += opsb[s];
        const int opn = opsb[s + 1];
        float gx0 = 0.f, gx1 = 0.f;
        if (khalf == 0) {                       // wave-uniform branch
            const float* gxb = gxc + ((size_t)s * Bb + b) * G4;
            gx0 = gxb[rr];
            gx1 = gxb[rr + 256];
        }

        const float hv = h_st[pt * Hh + khalf * 64 + lane];
        float a0 = 0.f, a1 = 0.f, a2 = 0.f, a3 = 0.f;
#pragma unroll
        for (int j = 0; j < 16; ++j) {
            const float4 W0 = w0[j];
            const float4 W1 = w1[j];
            const float h0 = rl(hv, 4 * j + 0);
            const float h1 = rl(hv, 4 * j + 1);
            const float h2 = rl(hv, 4 * j + 2);
            const float h3 = rl(hv, 4 * j + 3);
            a0 = fmaf(W0.x, h0, a0); a2 = fmaf(W1.x, h0, a2);
            a1 = fmaf(W0.y, h1, a1); a3 = fmaf(W1.y, h1, a3);
            a0 = fmaf(W0.z, h2, a0); a2 = fmaf(W1.z, h2, a2);
            a1 = fmaf(W0.w, h3, a1); a3 = fmaf(W1.w, h3, a3);
        }
        gpart[khalf * G4 + rr]       = (a0 + a1) + gx0;
        gpart[khalf * G4 + 256 + rr] = (a2 + a3) + gx1;
        __syncthreads();

        if (tid < Hh) {
            const int h = tid;
            const float gi = gpart[h]        + gpart[G4 + h];
            const float gf = gpart[128 + h]  + gpart[G4 + 128 + h];
            const float gg = gpart[256 + h]  + gpart[G4 + 256 + h];
            const float go = gpart[384 + h]  + gpart[G4 + 384 + h];
            const float cc = c_st[pt * Hh + h];
            const float ch = h_st[pt * Hh + h];
            const float ph = h_st[((pt + S1 - 1) % S1) * Hh + h];
            const float nc = sigm(gf) * cc + sigm(gi) * tanhx(gg);
            const float nh = sigm(go) * tanhx(nc);
            c_st[(pt + 1) * Hh + h] = nc;
            h_st[(pt + 1) * Hh + h] = nh;
            const float opf = (float)opn;
            const float af = fabsf(opf);
            const float ret = (nh * (1.f + opf) + ph * (1.f - opf)) * af + ch * (1.f - af);
            out[((size_t)(t0 + s) * Bb + b) * Hh + h] = ret;
        }
        __syncthreads();
    }

    if (!last) {
        float* hs = h_save + (size_t)b * (S1 * Hh);
        float* cs = c_save + (size_t)b * (S1 * Hh);
        for (int i = tid; i < S1 * Hh; i += 512) { hs[i] = h_st[i]; cs[i] = c_st[i]; }
        if (tid == 0) pt_save[b] = pt;
    }
}

extern "C" void kernel_launch(void* const* d_in, const int* in_sizes, int n_in,
                              void* d_out, int out_size, void* d_ws, size_t ws_size,
                              hipStream_t stream) {
    const float* inputs = (const float*)d_in[0];
    const int*   ops    = (const int*)d_in[1];
    const float* W_ih   = (const float*)d_in[2];
    const float* W_hh   = (const float*)d_in[3];
    const float* b_ih   = (const float*)d_in[4];
    const float* b_hh   = (const float*)d_in[5];
    const float* init_h = (const float*)d_in[6];
    const float* init_c = (const float*)d_in[7];
    float* out = (float*)d_out;

    // Workspace (~98.3 MB): gxbuf CH*B*512 fp32 = 64 MB; h/c_save 17 MB each.
    float* gxbuf  = (float*)d_ws;
    float* h_save = gxbuf + (size_t)CH * Bb * G4;
    float* c_save = h_save + (size_t)Bb * S1 * Hh;
    int*   pt_save = (int*)(c_save + (size_t)Bb * S1 * Hh);

    int t0 = 0;
    while (t0 < NSTEP) {
        const int steps = (NSTEP - t0 < CH) ? (NSTEP - t0) : CH;
        const int rows = steps * Bb;           // divisible by 64
        gx_gemm<<<rows / 64, 512, 0, stream>>>(
            inputs + (size_t)t0 * Bb * Ii, W_ih, b_ih, b_hh, gxbuf);
        rec_step<<<Bb, 512, 0, stream>>>(
            gxbuf, ops, W_hh, init_h, init_c, out,
            h_save, c_save, pt_save, t0, steps,
            (t0 == 0) ? 1 : 0, (t0 + steps >= NSTEP) ? 1 : 0);
        t0 += steps;
    }
}

// Round 3
// 2097.277 us; speedup vs baseline: 3.2093x; 1.0984x over previous
//
#include <hip/hip_runtime.h>
#include <cstdint>

#define Tt 512
#define Bb 512
#define Ii 128
#define Hh 128
#define G4 512   // 4*H
#define S1 65    // stack slots
#define CH 64    // steps per chunk
#define NSTEP 511
#define GROWS 128  // x rows staged per gx block

typedef float v2f __attribute__((ext_vector_type(2)));

__device__ __forceinline__ v2f fma2(v2f a, v2f b, v2f c) {
    return __builtin_elementwise_fma(a, b, c);
}
__device__ __forceinline__ float sigm(float x) {
    float e = __builtin_amdgcn_exp2f(x * -1.442695041f);
    return __builtin_amdgcn_rcpf(1.0f + e);
}
__device__ __forceinline__ float tanhx(float x) {
    float e = __builtin_amdgcn_exp2f(x * 2.885390082f);   // exp(2x)
    return 1.0f - 2.0f * __builtin_amdgcn_rcpf(e + 1.0f);
}

// ---------------- Input GEMM: gx = x @ W_ih^T + (b_ih + b_hh) ----------------
// 1024 threads = 16 waves. Wave w, lane l: gate g = w*32 + (l&31), k-half
// kh = l>>5. Thread holds W_ih[g][kh*64 .. +64) as 32 pinned float2 (64 VGPRs).
// x rows staged in LDS; read as 2-address-broadcast ds_read_b128 (free).
// Partial sums combined with one shfl_xor(32).
__global__ __launch_bounds__(1024, 4) void gx_gemm(
    const float* __restrict__ x,      // (rows, 128), chunk base
    const float* __restrict__ W_ih,   // (512, 128)
    const float* __restrict__ b_ih,
    const float* __restrict__ b_hh,
    float* __restrict__ gx)           // (rows, 512)
{
    const int tid = threadIdx.x;
    const int w = tid >> 6;
    const int l = tid & 63;
    const int g = w * 32 + (l & 31);
    const int kh = l >> 5;

    v2f wv[32];
    {
        const v2f* wp = (const v2f*)(W_ih + g * Ii + kh * 64);
#pragma unroll
        for (int i = 0; i < 32; ++i) wv[i] = wp[i];
#pragma unroll
        for (int i = 0; i < 32; ++i) asm volatile("" : "+v"(wv[i]));  // pin in VGPRs
    }
    const float bias = b_ih[g] + b_hh[g];

    __shared__ float xs[GROWS * Ii];  // 64 KB
    const size_t m0 = (size_t)blockIdx.x * GROWS;
    {
        const float4* src = (const float4*)(x + m0 * Ii);
        float4* dst = (float4*)xs;
#pragma unroll
        for (int j = 0; j < 4; ++j) dst[tid + j * 1024] = src[tid + j * 1024];
    }
    __syncthreads();

    for (int mi = 0; mi < GROWS; ++mi) {
        const float4* xr = (const float4*)(xs + mi * Ii + kh * 64);
        v2f acc = {0.f, 0.f};
#pragma unroll
        for (int i = 0; i < 16; ++i) {
            float4 xx = xr[i];
            v2f x0 = {xx.x, xx.y};
            v2f x1 = {xx.z, xx.w};
            acc = fma2(wv[2 * i], x0, acc);
            acc = fma2(wv[2 * i + 1], x1, acc);
        }
        float s = acc.x + acc.y;
        s += __shfl_xor(s, 32);
        if (l < 32) gx[(m0 + mi) * G4 + g] = s + bias;
    }
}

// ---------------- Recurrence: one block (1024 thr) per batch element --------
// Same thread layout as gx_gemm: gate g = w*32+(l&31), k-half kh = l>>5,
// 32 pinned float2 weights/thread. Stack state in LDS for the whole chunk.
__global__ __launch_bounds__(1024, 4) void rec_step(
    const float* __restrict__ gxc,    // (steps, B, 512) chunk
    const int* __restrict__ ops,      // (T, B)
    const float* __restrict__ W_hh,   // (512, 128)
    const float* __restrict__ init_h,
    const float* __restrict__ init_c,
    float* __restrict__ out,          // (NSTEP, B, H)
    float* __restrict__ h_save,
    float* __restrict__ c_save,
    int* __restrict__ pt_save,
    int t0, int steps, int first, int last)
{
    const int b = blockIdx.x;
    const int tid = threadIdx.x;
    const int w = tid >> 6;
    const int l = tid & 63;
    const int g = w * 32 + (l & 31);
    const int kh = l >> 5;

    __shared__ float h_st[S1 * Hh];   // 33.3 KB
    __shared__ float c_st[S1 * Hh];   // 33.3 KB
    __shared__ float gates[G4];       // 2 KB
    __shared__ int opsb[CH + 1];

    v2f wv[32];
    {
        const v2f* wp = (const v2f*)(W_hh + g * Hh + kh * 64);
#pragma unroll
        for (int i = 0; i < 32; ++i) wv[i] = wp[i];
#pragma unroll
        for (int i = 0; i < 32; ++i) asm volatile("" : "+v"(wv[i]));  // pin in VGPRs
    }

    if (first) {
        for (int i = tid; i < S1 * Hh; i += 1024) {
            h_st[i] = (i < Hh) ? init_h[i] : 0.f;
            c_st[i] = (i < Hh) ? init_c[i] : 0.f;
        }
    } else {
        const float* hs = h_save + (size_t)b * (S1 * Hh);
        const float* cs = c_save + (size_t)b * (S1 * Hh);
        for (int i = tid; i < S1 * Hh; i += 1024) { h_st[i] = hs[i]; c_st[i] = cs[i]; }
    }
    for (int i = tid; i <= steps; i += 1024) opsb[i] = ops[(size_t)(t0 + i) * Bb + b];
    int pt = first ? 0 : pt_save[b];
    __syncthreads();

    for (int s = 0; s < steps; ++s) {
        pt += opsb[s];
        const int opn = opsb[s + 1];
        const float gxv = gxc[((size_t)s * Bb + b) * G4 + g];  // prefetch

        const float4* hr = (const float4*)(h_st + pt * Hh + kh * 64);
        v2f acc = {0.f, 0.f};
#pragma unroll
        for (int i = 0; i < 16; ++i) {
            float4 hh = hr[i];
            v2f h0 = {hh.x, hh.y};
            v2f h1 = {hh.z, hh.w};
            acc = fma2(wv[2 * i], h0, acc);
            acc = fma2(wv[2 * i + 1], h1, acc);
        }
        float sv = acc.x + acc.y;
        sv += __shfl_xor(sv, 32);          // combine k-halves in-wave
        if (l < 32) gates[g] = sv + gxv;
        __syncthreads();

        if (tid < Hh) {
            const int h = tid;
            const float gi = gates[h];
            const float gf = gates[Hh + h];
            const float gg = gates[2 * Hh + h];
            const float go = gates[3 * Hh + h];
            const float cc = c_st[pt * Hh + h];
            const float ch = h_st[pt * Hh + h];
            const float ph = h_st[((pt + S1 - 1) % S1) * Hh + h];
            const float nc = sigm(gf) * cc + sigm(gi) * tanhx(gg);
            const float nh = sigm(go) * tanhx(nc);
            c_st[(pt + 1) * Hh + h] = nc;
            h_st[(pt + 1) * Hh + h] = nh;
            const float opf = (float)opn;
            const float af = fabsf(opf);
            const float ret = (nh * (1.f + opf) + ph * (1.f - opf)) * af + ch * (1.f - af);
            out[((size_t)(t0 + s) * Bb + b) * Hh + h] = ret;
        }
        __syncthreads();
    }

    if (!last) {
        float* hs = h_save + (size_t)b * (S1 * Hh);
        float* cs = c_save + (size_t)b * (S1 * Hh);
        for (int i = tid; i < S1 * Hh; i += 1024) { hs[i] = h_st[i]; cs[i] = c_st[i]; }
        if (tid == 0) pt_save[b] = pt;
    }
}

extern "C" void kernel_launch(void* const* d_in, const int* in_sizes, int n_in,
                              void* d_out, int out_size, void* d_ws, size_t ws_size,
                              hipStream_t stream) {
    const float* inputs = (const float*)d_in[0];
    const int*   ops    = (const int*)d_in[1];
    const float* W_ih   = (const float*)d_in[2];
    const float* W_hh   = (const float*)d_in[3];
    const float* b_ih   = (const float*)d_in[4];
    const float* b_hh   = (const float*)d_in[5];
    const float* init_h = (const float*)d_in[6];
    const float* init_c = (const float*)d_in[7];
    float* out = (float*)d_out;

    // Workspace (~98.3 MB): gxbuf CH*B*512 fp32 = 64 MB; h/c_save 17 MB each.
    float* gxbuf  = (float*)d_ws;
    float* h_save = gxbuf + (size_t)CH * Bb * G4;
    float* c_save = h_save + (size_t)Bb * S1 * Hh;
    int*   pt_save = (int*)(c_save + (size_t)Bb * S1 * Hh);

    int t0 = 0;
    while (t0 < NSTEP) {
        const int steps = (NSTEP - t0 < CH) ? (NSTEP - t0) : CH;
        const int rows = steps * Bb;           // divisible by GROWS (128)
        gx_gemm<<<rows / GROWS, 1024, 0, stream>>>(
            inputs + (size_t)t0 * Bb * Ii, W_ih, b_ih, b_hh, gxbuf);
        rec_step<<<Bb, 1024, 0, stream>>>(
            gxbuf, ops, W_hh, init_h, init_c, out,
            h_save, c_save, pt_save, t0, steps,
            (t0 == 0) ? 1 : 0, (t0 + steps >= NSTEP) ? 1 : 0);
        t0 += steps;
    }
}